// Round 1
// baseline (1507.498 us; speedup 1.0000x reference)
//
#include <hip/hip_runtime.h>
#include <math.h>

// Problem constants
#define QN 2048
#define CN 10
#define SN 16
#define DN 256
#define H1N 256
#define H2N 128
#define H3N 64
#define H4N 10

// ---------------------------------------------------------------------------
// Kernel 1: layer-1 factorization.
//   A[q][j]  = b1[j] + sum_d queries[q][d] * W1[d][j]          (q < 2048)
//   B[i][j]  =         sum_d supports[i][d] * W1[256+d][j]     (i < 160)
// One block (256 threads) computes 4 rows; thread j owns column j.
// ---------------------------------------------------------------------------
__global__ __launch_bounds__(256) void k_pre(
    const float* __restrict__ queries, const float* __restrict__ supports,
    const float* __restrict__ W1, const float* __restrict__ b1,
    float* __restrict__ A, float* __restrict__ Bm) {
  __shared__ float xs[4][DN];
  const int bid = blockIdx.x;
  const int t = threadIdx.x;
  const bool isA = bid < (QN / 4);
  const int row0 = isA ? bid * 4 : (bid - QN / 4) * 4;
  const float* src = isA ? (queries + (size_t)row0 * DN) : (supports + (size_t)row0 * DN);
  for (int r = 0; r < 4; ++r) xs[r][t] = src[r * DN + t];
  __syncthreads();
  const float* w = W1 + (isA ? 0 : DN * H1N) + t;  // column t
  float acc0 = 0.f, acc1 = 0.f, acc2 = 0.f, acc3 = 0.f;
#pragma unroll 8
  for (int d = 0; d < DN; ++d) {
    const float wv = w[(size_t)d * H1N];
    acc0 += xs[0][d] * wv;
    acc1 += xs[1][d] * wv;
    acc2 += xs[2][d] * wv;
    acc3 += xs[3][d] * wv;
  }
  const float bias = isA ? b1[t] : 0.f;
  float* dst = isA ? A : Bm;
  dst[(row0 + 0) * H1N + t] = acc0 + bias;
  dst[(row0 + 1) * H1N + t] = acc1 + bias;
  dst[(row0 + 2) * H1N + t] = acc2 + bias;
  dst[(row0 + 3) * H1N + t] = acc3 + bias;
}

// ---------------------------------------------------------------------------
// Kernel 2: fused layers 2-4 + tanh + mean + item-sum.
// One block (256 threads) handles one (q, c) pair = 16 support items.
// Activations staged in LDS, k-major, padded S+1 against bank conflicts.
// ---------------------------------------------------------------------------
#define SP (SN + 1)

__global__ __launch_bounds__(256) void k_main(
    const float* __restrict__ A, const float* __restrict__ Bm,
    const float* __restrict__ W2, const float* __restrict__ b2,
    const float* __restrict__ W3, const float* __restrict__ b3,
    const float* __restrict__ W4, const float* __restrict__ b4,
    float* __restrict__ out) {
  __shared__ float h1t[DN][SP];   // ~17.4 KB
  __shared__ float h2t[H2N][SP];  // ~8.7 KB
  __shared__ float h3t[H3N][SP];  // ~4.4 KB
  __shared__ float outv[SN][H4N];
  __shared__ float item[SN];

  const int bid = blockIdx.x;
  const int q = bid / CN;
  const int c = bid % CN;
  const int t = threadIdx.x;
  const float* Aq = A + (size_t)q * H1N;

  // ---- phase 1: h1 = relu(Aq + B[c*16+s]) -> h1t[k][s]
  {
    const int s = t >> 4;   // 0..15 (item)
    const int k0 = t & 15;  // 0..15
    const float* Brow = Bm + (size_t)(c * SN + s) * H1N;
#pragma unroll
    for (int m = 0; m < 16; ++m) {
      const int k = m * 16 + k0;
      const float v = Aq[k] + Brow[k];
      h1t[k][s] = v > 0.f ? v : 0.f;
    }
  }
  __syncthreads();

  // ---- phase 2: h2 = relu(h1 @ W2 + b2); thread: item s, 8 cols
  {
    const int s = t & 15;
    const int j0 = (t >> 4) * 8;  // 0,8,...,120
    float acc[8];
#pragma unroll
    for (int i = 0; i < 8; ++i) acc[i] = b2[j0 + i];
#pragma unroll 4
    for (int k = 0; k < H1N; ++k) {
      const float h = h1t[k][s];
      const float4 w0 = *reinterpret_cast<const float4*>(W2 + (size_t)k * H2N + j0);
      const float4 w1 = *reinterpret_cast<const float4*>(W2 + (size_t)k * H2N + j0 + 4);
      acc[0] += h * w0.x; acc[1] += h * w0.y; acc[2] += h * w0.z; acc[3] += h * w0.w;
      acc[4] += h * w1.x; acc[5] += h * w1.y; acc[6] += h * w1.z; acc[7] += h * w1.w;
    }
#pragma unroll
    for (int i = 0; i < 8; ++i) h2t[j0 + i][s] = acc[i] > 0.f ? acc[i] : 0.f;
  }
  __syncthreads();

  // ---- phase 3: h3 = relu(h2 @ W3 + b3); thread: item s, 4 cols
  {
    const int s = t & 15;
    const int j0 = (t >> 4) * 4;  // 0,4,...,60
    float acc[4];
#pragma unroll
    for (int i = 0; i < 4; ++i) acc[i] = b3[j0 + i];
#pragma unroll 4
    for (int k = 0; k < H2N; ++k) {
      const float h = h2t[k][s];
      const float4 w0 = *reinterpret_cast<const float4*>(W3 + (size_t)k * H3N + j0);
      acc[0] += h * w0.x; acc[1] += h * w0.y; acc[2] += h * w0.z; acc[3] += h * w0.w;
    }
#pragma unroll
    for (int i = 0; i < 4; ++i) h3t[j0 + i][s] = acc[i] > 0.f ? acc[i] : 0.f;
  }
  __syncthreads();

  // ---- phase 4: out = tanh(h3 @ W4 + b4); 160 threads: (item s, output o)
  if (t < SN * H4N) {
    const int s = t / H4N;
    const int o = t % H4N;
    float acc = b4[o];
#pragma unroll 8
    for (int k = 0; k < H3N; ++k) acc += h3t[k][s] * W4[k * H4N + o];
    outv[s][o] = tanhf(acc);
  }
  __syncthreads();

  // mean over 10 outputs per item
  if (t < SN) {
    float sum = 0.f;
#pragma unroll
    for (int o = 0; o < H4N; ++o) sum += outv[t][o];
    item[t] = sum * (1.0f / H4N);
  }
  __syncthreads();

  // sum over 16 items -> scores[q][c]
  if (t == 0) {
    float sc = 0.f;
#pragma unroll
    for (int s = 0; s < SN; ++s) sc += item[s];
    out[(size_t)q * CN + c] = sc;
  }
}

// ---------------------------------------------------------------------------
extern "C" void kernel_launch(void* const* d_in, const int* in_sizes, int n_in,
                              void* d_out, int out_size, void* d_ws, size_t ws_size,
                              hipStream_t stream) {
  const float* queries  = (const float*)d_in[0];
  const float* supports = (const float*)d_in[1];
  const float* W1 = (const float*)d_in[2];
  const float* b1 = (const float*)d_in[3];
  const float* W2 = (const float*)d_in[4];
  const float* b2 = (const float*)d_in[5];
  const float* W3 = (const float*)d_in[6];
  const float* b3 = (const float*)d_in[7];
  const float* W4 = (const float*)d_in[8];
  const float* b4 = (const float*)d_in[9];
  float* out = (float*)d_out;

  // workspace: A [2048][256] fp32, then B [160][256] fp32  (~2.26 MB)
  float* A  = (float*)d_ws;
  float* Bm = A + (size_t)QN * H1N;

  hipLaunchKernelGGL(k_pre, dim3(QN / 4 + (CN * SN) / 4), dim3(256), 0, stream,
                     queries, supports, W1, b1, A, Bm);
  hipLaunchKernelGGL(k_main, dim3(QN * CN), dim3(256), 0, stream,
                     A, Bm, W2, b2, W3, b3, W4, b4, out);
}

// Round 2
// 533.073 us; speedup vs baseline: 2.8279x; 2.8279x over previous
//
#include <hip/hip_runtime.h>
#include <math.h>

// Problem constants
#define QN 2048
#define CN 10
#define SN 16
#define DN 256
#define H1N 256
#define H2N 128
#define H3N 64
#define H4N 10
#define NROW 160        // C*S support rows
#define TM 64           // rows per k_main block

// ---------------------------------------------------------------------------
// Kernel 1: layer-1 factorization, TRANSPOSED outputs.
//   A_T[j][q] = b1[j] + sum_d queries[q][d] * W1[d][j]       (j<256, q<2048)
//   B_T[j][i] =         sum_d supports[i][d] * W1[256+d][j]  (i<160)
// One block (256 threads) computes 4 rows; thread j owns column j, writes
// a float4 of 4 consecutive q (or i) -> aligned 16B stores.
// ---------------------------------------------------------------------------
__global__ __launch_bounds__(256) void k_pre(
    const float* __restrict__ queries, const float* __restrict__ supports,
    const float* __restrict__ W1, const float* __restrict__ b1,
    float* __restrict__ A_T, float* __restrict__ B_T) {
  __shared__ float xs[4][DN];
  const int bid = blockIdx.x;
  const int t = threadIdx.x;
  const bool isA = bid < (QN / 4);
  const int row0 = isA ? bid * 4 : (bid - QN / 4) * 4;
  const float* src = isA ? (queries + (size_t)row0 * DN) : (supports + (size_t)row0 * DN);
  for (int r = 0; r < 4; ++r) xs[r][t] = src[r * DN + t];
  __syncthreads();
  const float* w = W1 + (isA ? 0 : DN * H1N) + t;  // column t
  float acc0 = 0.f, acc1 = 0.f, acc2 = 0.f, acc3 = 0.f;
#pragma unroll 8
  for (int d = 0; d < DN; ++d) {
    const float wv = w[(size_t)d * H1N];
    acc0 += xs[0][d] * wv;
    acc1 += xs[1][d] * wv;
    acc2 += xs[2][d] * wv;
    acc3 += xs[3][d] * wv;
  }
  if (isA) {
    const float bias = b1[t];
    float4 v = make_float4(acc0 + bias, acc1 + bias, acc2 + bias, acc3 + bias);
    *reinterpret_cast<float4*>(A_T + (size_t)t * QN + row0) = v;
  } else {
    float4 v = make_float4(acc0, acc1, acc2, acc3);
    *reinterpret_cast<float4*>(B_T + (size_t)t * NROW + row0) = v;
  }
}

// ---------------------------------------------------------------------------
// Kernel 2: tiled-GEMM fused layers 2-4.
// Block = 64 rows (r = (q*10+c)*16+s). 256 threads.
//   GEMM2: h2[64][128] = relu(h1 @ W2 + b2), h1 built on the fly from A_T/B_T.
//     k-chunks of 32 staged in LDS; per-thread 8x4 register tile.
//   GEMM3: h3[64][64]  = relu(h2 @ W3 + b3); per-thread 4x4 tile.
//   Layer4: 10 outs, tanh, mean, sum over 16 items -> 4 scores per block.
// LDS: R1 24KB (staging, reused), R2 48.5KB (h2s + h3s). 2 blocks/CU.
// ---------------------------------------------------------------------------
__global__ __launch_bounds__(256, 2) void k_main(
    const float* __restrict__ A_T, const float* __restrict__ B_T,
    const float* __restrict__ W2, const float* __restrict__ b2,
    const float* __restrict__ W3, const float* __restrict__ b3,
    const float* __restrict__ W4, const float* __restrict__ b4,
    float* __restrict__ out) {
  __shared__ __align__(16) float R1[32 * 64 + 32 * 128];   // 6144 floats, 24KB
  __shared__ __align__(16) float R2[64 * 129 + 64 * 65];   // 12416 floats, 48.5KB
  float* As  = R1;             // [32][64] k-major h1 chunk
  float* Ws2 = R1 + 2048;      // [32][128]
  float* h2s = R2;             // [64][129] row-major (pad vs bank conflict)
  float* h3s = R2 + 64 * 129;  // [64][65]

  const int t = threadIdx.x;
  const int row0 = blockIdx.x * TM;

  // --- GEMM2: per-thread 8 rows x 4 cols ---
  const int tx = t & 7, ty = t >> 3;
  const int i0 = tx * 8, j0 = ty * 4;
  const int li = t & 63;   // staging lane row (constant across iters)
  const int wv = t >> 6;   // wave id 0..3
  const int gr = row0 + li;
  const int gq = gr / NROW;          // query index for this row
  const int gb = gr - gq * NROW;     // support-row index

  float acc[8][4];
#pragma unroll
  for (int r = 0; r < 8; ++r)
#pragma unroll
    for (int c = 0; c < 4; ++c) acc[r][c] = 0.f;

  for (int kc = 0; kc < H1N; kc += 32) {
    // stage h1 chunk: As[kk][i] = relu(A_T[kc+kk][q(i)] + B_T[kc+kk][b(i)])
#pragma unroll
    for (int it = 0; it < 8; ++it) {
      const int kk = it * 4 + wv;
      const float v = A_T[(size_t)(kc + kk) * QN + gq] + B_T[(kc + kk) * NROW + gb];
      As[kk * 64 + li] = fmaxf(v, 0.f);
    }
    // stage W2 chunk (rows kc..kc+31 contiguous): coalesced float4
#pragma unroll
    for (int it = 0; it < 4; ++it) {
      const int idx = it * 256 + t;
      *reinterpret_cast<float4*>(&Ws2[idx * 4]) =
          *reinterpret_cast<const float4*>(W2 + (size_t)kc * H2N + idx * 4);
    }
    __syncthreads();
#pragma unroll
    for (int kk = 0; kk < 32; ++kk) {
      const float4 a0 = *reinterpret_cast<const float4*>(&As[kk * 64 + i0]);
      const float4 a1 = *reinterpret_cast<const float4*>(&As[kk * 64 + i0 + 4]);
      const float4 w  = *reinterpret_cast<const float4*>(&Ws2[kk * 128 + j0]);
      const float ar[8] = {a0.x, a0.y, a0.z, a0.w, a1.x, a1.y, a1.z, a1.w};
      const float wr[4] = {w.x, w.y, w.z, w.w};
#pragma unroll
      for (int r = 0; r < 8; ++r)
#pragma unroll
        for (int c = 0; c < 4; ++c) acc[r][c] += ar[r] * wr[c];
    }
    __syncthreads();
  }

  // bias + relu -> h2s (row-major, pad 129)
  {
    const float4 bb = *reinterpret_cast<const float4*>(b2 + j0);
    const float br[4] = {bb.x, bb.y, bb.z, bb.w};
#pragma unroll
    for (int r = 0; r < 8; ++r)
#pragma unroll
      for (int c = 0; c < 4; ++c)
        h2s[(i0 + r) * 129 + j0 + c] = fmaxf(acc[r][c] + br[c], 0.f);
  }

  // --- GEMM3: per-thread 4 rows x 4 cols over K=128 in 2 chunks of 64 ---
  const int tx3 = t & 15, ty3 = t >> 4;
  const int i3 = tx3 * 4, j3 = ty3 * 4;
  float acc3[4][4];
#pragma unroll
  for (int r = 0; r < 4; ++r)
#pragma unroll
    for (int c = 0; c < 4; ++c) acc3[r][c] = 0.f;

  float* Ws3 = R1;  // [64][64] (R1 free after GEMM2's trailing sync)
  for (int k2c = 0; k2c < 2; ++k2c) {
#pragma unroll
    for (int it = 0; it < 4; ++it) {
      const int idx = it * 256 + t;
      *reinterpret_cast<float4*>(&Ws3[idx * 4]) =
          *reinterpret_cast<const float4*>(W3 + (size_t)k2c * 64 * H3N + idx * 4);
    }
    __syncthreads();  // also orders h2s writes before reads (k2c==0)
#pragma unroll
    for (int kk = 0; kk < 64; ++kk) {
      const float4 w = *reinterpret_cast<const float4*>(&Ws3[kk * 64 + j3]);
      const int k2 = k2c * 64 + kk;
      float a[4];
#pragma unroll
      for (int r = 0; r < 4; ++r) a[r] = h2s[(i3 + r) * 129 + k2];
      const float wr[4] = {w.x, w.y, w.z, w.w};
#pragma unroll
      for (int r = 0; r < 4; ++r)
#pragma unroll
        for (int c = 0; c < 4; ++c) acc3[r][c] += a[r] * wr[c];
    }
    __syncthreads();
  }

  // bias + relu -> h3s
  {
    const float4 bb = *reinterpret_cast<const float4*>(b3 + j3);
    const float br[4] = {bb.x, bb.y, bb.z, bb.w};
#pragma unroll
    for (int r = 0; r < 4; ++r)
#pragma unroll
      for (int c = 0; c < 4; ++c)
        h3s[(i3 + r) * 65 + j3 + c] = fmaxf(acc3[r][c] + br[c], 0.f);
  }

  // --- Layer 4 + tanh + mean + item-sum ---
  float* w4s = R1;               // 640 floats
  float* partial = R1 + 640;     // [64][4]
  float* iscore = R1 + 640 + 256;  // [64]
#pragma unroll
  for (int it = 0; it < 3; ++it) {
    const int idx = it * 256 + t;
    if (idx < H3N * H4N) w4s[idx] = W4[idx];
  }
  __syncthreads();  // h3s + w4s ready

  {
    const int row = li;    // 0..63
    const int g = wv;      // 0..3 (uniform per wave)
    float o0 = 0.f, o1 = 0.f, o2 = 0.f;
#pragma unroll
    for (int k3 = 0; k3 < H3N; ++k3) {
      const float h = h3s[row * 65 + k3];
      o0 += h * w4s[k3 * H4N + g];
      o1 += h * w4s[k3 * H4N + g + 4];
      if (g < 2) o2 += h * w4s[k3 * H4N + g + 8];
    }
    float ssum = tanhf(o0 + b4[g]) + tanhf(o1 + b4[g + 4]);
    if (g < 2) ssum += tanhf(o2 + b4[g + 8]);
    partial[row * 4 + g] = ssum;
  }
  __syncthreads();
  if (t < TM) {
    iscore[t] = (partial[t * 4 + 0] + partial[t * 4 + 1] +
                 partial[t * 4 + 2] + partial[t * 4 + 3]) * (1.0f / H4N);
  }
  __syncthreads();
  if (t < 4) {
    float sc = 0.f;
#pragma unroll
    for (int s = 0; s < SN; ++s) sc += iscore[t * SN + s];
    out[(size_t)blockIdx.x * 4 + t] = sc;
  }
}

// ---------------------------------------------------------------------------
extern "C" void kernel_launch(void* const* d_in, const int* in_sizes, int n_in,
                              void* d_out, int out_size, void* d_ws, size_t ws_size,
                              hipStream_t stream) {
  const float* queries  = (const float*)d_in[0];
  const float* supports = (const float*)d_in[1];
  const float* W1 = (const float*)d_in[2];
  const float* b1 = (const float*)d_in[3];
  const float* W2 = (const float*)d_in[4];
  const float* b2 = (const float*)d_in[5];
  const float* W3 = (const float*)d_in[6];
  const float* b3 = (const float*)d_in[7];
  const float* W4 = (const float*)d_in[8];
  const float* b4 = (const float*)d_in[9];
  float* out = (float*)d_out;

  // workspace: A_T [256][2048] fp32, B_T [256][160] fp32  (~2.26 MB)
  float* A_T = (float*)d_ws;
  float* B_T = A_T + (size_t)H1N * QN;

  hipLaunchKernelGGL(k_pre, dim3(QN / 4 + NROW / 4), dim3(256), 0, stream,
                     queries, supports, W1, b1, A_T, B_T);
  hipLaunchKernelGGL(k_main, dim3((QN * CN * SN) / TM), dim3(256), 0, stream,
                     A_T, B_T, W2, b2, W3, b3, W4, b4, out);
}

// Round 5
// 89.688 us; speedup vs baseline: 16.8082x; 5.9436x over previous
//
#include <hip/hip_runtime.h>
#include <math.h>

// Problem constants
#define QN 2048
#define CN 10
#define SN 16
#define DN 256
#define H1N 256
#define H2N 128
#define H3N 64
#define H4N 10
#define NROW 160        // C*S support rows

typedef __attribute__((ext_vector_type(8)))  short  bf16x8s;  // 8 bf16 = 4 VGPR
typedef __attribute__((ext_vector_type(4)))  float  f32x4;
typedef __attribute__((ext_vector_type(16))) float  f32x16;

static __device__ __forceinline__ unsigned short f2bf(float f) {
  unsigned int u = __builtin_bit_cast(unsigned int, f);
  u += 0x7fffu + ((u >> 16) & 1u);   // round-to-nearest-even
  return (unsigned short)(u >> 16);
}

// ---------------------------------------------------------------------------
// Kernel 1: layer-1 factorization (fp32, row-major outputs).
//   A[q][j]  = b1[j] + sum_d queries[q][d] * W1[d][j]
//   Bm[i][j] =         sum_d supports[i][d] * W1[256+d][j]
// ---------------------------------------------------------------------------
__global__ __launch_bounds__(256) void k_pre(
    const float* __restrict__ queries, const float* __restrict__ supports,
    const float* __restrict__ W1, const float* __restrict__ b1,
    float* __restrict__ A, float* __restrict__ Bm) {
  __shared__ float xs[4][DN];
  const int bid = blockIdx.x;
  const int t = threadIdx.x;
  const bool isA = bid < (QN / 4);
  const int row0 = isA ? bid * 4 : (bid - QN / 4) * 4;
  const float* src = isA ? (queries + (size_t)row0 * DN) : (supports + (size_t)row0 * DN);
  for (int r = 0; r < 4; ++r) xs[r][t] = src[r * DN + t];
  __syncthreads();
  const float* w = W1 + (isA ? 0 : DN * H1N) + t;  // column t
  float acc0 = 0.f, acc1 = 0.f, acc2 = 0.f, acc3 = 0.f;
#pragma unroll 8
  for (int d = 0; d < DN; ++d) {
    const float wv = w[(size_t)d * H1N];
    acc0 += xs[0][d] * wv;
    acc1 += xs[1][d] * wv;
    acc2 += xs[2][d] * wv;
    acc3 += xs[3][d] * wv;
  }
  const float bias = isA ? b1[t] : 0.f;
  float* dst = isA ? A : Bm;
  dst[(row0 + 0) * H1N + t] = acc0 + bias;
  dst[(row0 + 1) * H1N + t] = acc1 + bias;
  dst[(row0 + 2) * H1N + t] = acc2 + bias;
  dst[(row0 + 3) * H1N + t] = acc3 + bias;
}

// ---------------------------------------------------------------------------
// Kernel 1b: pack W2/W3/W4 into fragment-linear bf16 buffers.
// fb2: 64 frags (ct 0..3, ks 0..15) of v_mfma_f32_32x32x16_bf16 B-operand:
//      lane l, elem j  <-  W2[ks*16 + (l>>5)*8 + j][ct*32 + (l&31)]
// fb3: 16 frags (ct 0..1, ks 0..7)  of same, for W3.
// fb4:  2 frags (ks 0..1) of 16x16x32 B-operand, cols >=10 zero-padded:
//      lane l, elem j  <-  W4[ks*32 + (l>>4)*8 + j][l&15]
// Each frag = 64 lanes * 8 bf16 = 512 ushorts.
// ---------------------------------------------------------------------------
__global__ __launch_bounds__(64) void k_wpack(
    const float* __restrict__ W2, const float* __restrict__ W3,
    const float* __restrict__ W4,
    ushort* __restrict__ fb2, ushort* __restrict__ fb3, ushort* __restrict__ fb4) {
  const int l = threadIdx.x;
  const int f = blockIdx.x;
  ushort o[8];
  if (f < 64) {
    const int ct = f >> 4, ks = f & 15;
    const int col = ct * 32 + (l & 31);
    const int k0 = ks * 16 + (l >> 5) * 8;
#pragma unroll
    for (int j = 0; j < 8; ++j) o[j] = f2bf(W2[(size_t)(k0 + j) * H2N + col]);
#pragma unroll
    for (int j = 0; j < 8; ++j) fb2[(size_t)f * 512 + l * 8 + j] = o[j];
  } else if (f < 80) {
    const int g = f - 64;
    const int ct = g >> 3, ks = g & 7;
    const int col = ct * 32 + (l & 31);
    const int k0 = ks * 16 + (l >> 5) * 8;
#pragma unroll
    for (int j = 0; j < 8; ++j) o[j] = f2bf(W3[(size_t)(k0 + j) * H3N + col]);
#pragma unroll
    for (int j = 0; j < 8; ++j) fb3[(size_t)g * 512 + l * 8 + j] = o[j];
  } else {
    const int ks = f - 80;
    const int col = l & 15;
    const int k0 = ks * 32 + (l >> 4) * 8;
#pragma unroll
    for (int j = 0; j < 8; ++j)
      o[j] = (col < H4N) ? f2bf(W4[(size_t)(k0 + j) * H4N + col]) : (ushort)0;
#pragma unroll
    for (int j = 0; j < 8; ++j) fb4[(size_t)ks * 512 + l * 8 + j] = o[j];
  }
}

// ---------------------------------------------------------------------------
// Kernel 2: MFMA layers 2-4 + tanh + mean + item-sum.
// Block = 64 rows, 4 waves in 2x2 (wr = row-half, wc = col-half).
// LDS activations bf16, XOR-swizzled (byte ^= (row&7)<<4) vs bank conflicts.
//   GEMM2 (32x32x16): rows 32wr..+32, cols 64wc..+64; B2 in 128 VGPRs;
//                     1 A ds_read_b128 feeds 2 MFMAs.
//   GEMM3 (32x32x16): rows 32wr..+32, cols 32wc..+32.
//   GEMM4 (16x16x32): wave wid -> its own 16 rows (one (q,c) group), 10 cols.
// ---------------------------------------------------------------------------
__global__ __launch_bounds__(256, 2) void k_main(
    const float* __restrict__ A, const float* __restrict__ Bm,
    const ushort* __restrict__ fb2, const ushort* __restrict__ fb3,
    const ushort* __restrict__ fb4,
    const float* __restrict__ b2, const float* __restrict__ b3,
    const float* __restrict__ b4, float* __restrict__ out) {
  __shared__ __align__(16) unsigned char smem[64 * 512 + 64 * 256 + 64 * 128];
  unsigned char* h1s = smem;                       // [64][256 bf16] swizzled
  unsigned char* h2s = smem + 64 * 512;            // [64][128 bf16] swizzled
  unsigned char* h3s = smem + 64 * 512 + 64 * 256; // [64][64 bf16]  swizzled

  const int t = threadIdx.x;
  const int wid = t >> 6;
  const int l = t & 63;
  const int l31 = l & 31;
  const int l15 = l & 15;
  const int sw = (l & 7) << 4;
  const int wr = wid >> 1, wc = wid & 1;

  // ---- B2 fragments: 2 col-tiles x 16 k-steps, coalesced global loads
  bf16x8s B2[2][16];
  const bf16x8s* fb2v = (const bf16x8s*)fb2;
#pragma unroll
  for (int ct = 0; ct < 2; ++ct) {
    const int ctg = wc * 2 + ct;
#pragma unroll
    for (int ks = 0; ks < 16; ++ks) B2[ct][ks] = fb2v[(ctg * 16 + ks) * 64 + l];
  }

  // ---- stage h1 = relu(A[q] + Bm[b]) -> LDS bf16 (coalesced 1KB/row reads)
  const int rg0 = blockIdx.x * 64;
#pragma unroll 4
  for (int r = 0; r < 16; ++r) {
    const int row = wid * 16 + r;           // wave-uniform
    const int rg = rg0 + row;
    const int q = rg / NROW;
    const int b = rg - q * NROW;
    const float4 av = *(const float4*)(A + (size_t)q * DN + l * 4);
    const float4 bv = *(const float4*)(Bm + (size_t)b * DN + l * 4);
    ushort4 o;
    o.x = f2bf(fmaxf(av.x + bv.x, 0.f));
    o.y = f2bf(fmaxf(av.y + bv.y, 0.f));
    o.z = f2bf(fmaxf(av.z + bv.z, 0.f));
    o.w = f2bf(fmaxf(av.w + bv.w, 0.f));
    *(ushort4*)(h1s + row * 512 + ((l * 8) ^ ((row & 7) << 4))) = o;
  }
  __syncthreads();

  // ---- GEMM2: h2 = relu(h1 @ W2 + b2)
  f32x16 acc2a, acc2b;
#pragma unroll
  for (int i = 0; i < 16; ++i) { acc2a[i] = 0.f; acc2b[i] = 0.f; }
  {
    const unsigned char* abase = h1s + (32 * wr + l31) * 512;
    const int kh = (l >> 5) * 16;
#pragma unroll
    for (int ks = 0; ks < 16; ++ks) {
      const bf16x8s a = *(const bf16x8s*)(abase + ((ks * 32 + kh) ^ sw));
      acc2a = __builtin_amdgcn_mfma_f32_32x32x16_bf16(a, B2[0][ks], acc2a, 0, 0, 0);
      acc2b = __builtin_amdgcn_mfma_f32_32x32x16_bf16(a, B2[1][ks], acc2b, 0, 0, 0);
    }
  }
  {
    const int c0 = 64 * wc + l31;
    const float bias0 = b2[c0], bias1 = b2[c0 + 32];
    const int cb0 = c0 * 2;
#pragma unroll
    for (int reg = 0; reg < 16; ++reg) {
      const int row = 32 * wr + (reg & 3) + 8 * (reg >> 2) + 4 * (l >> 5);
      const int rsw = (row & 7) << 4;
      *(ushort*)(h2s + row * 256 + (cb0 ^ rsw)) =
          f2bf(fmaxf(acc2a[reg] + bias0, 0.f));
      *(ushort*)(h2s + row * 256 + ((cb0 + 64) ^ rsw)) =
          f2bf(fmaxf(acc2b[reg] + bias1, 0.f));
    }
  }
  __syncthreads();

  // ---- GEMM3: h3 = relu(h2 @ W3 + b3)
  bf16x8s B3[8];
  const bf16x8s* fb3v = (const bf16x8s*)fb3;
#pragma unroll
  for (int ks = 0; ks < 8; ++ks) B3[ks] = fb3v[(wc * 8 + ks) * 64 + l];
  f32x16 acc3;
#pragma unroll
  for (int i = 0; i < 16; ++i) acc3[i] = 0.f;
  {
    const unsigned char* abase = h2s + (32 * wr + l31) * 256;
    const int kh = (l >> 5) * 16;
#pragma unroll
    for (int ks = 0; ks < 8; ++ks) {
      const bf16x8s a = *(const bf16x8s*)(abase + ((ks * 32 + kh) ^ sw));
      acc3 = __builtin_amdgcn_mfma_f32_32x32x16_bf16(a, B3[ks], acc3, 0, 0, 0);
    }
  }
  {
    const int c = 32 * wc + l31;
    const float bias = b3[c];
#pragma unroll
    for (int reg = 0; reg < 16; ++reg) {
      const int row = 32 * wr + (reg & 3) + 8 * (reg >> 2) + 4 * (l >> 5);
      const int rsw = (row & 7) << 4;
      *(ushort*)(h3s + row * 128 + ((c * 2) ^ rsw)) =
          f2bf(fmaxf(acc3[reg] + bias, 0.f));
    }
  }
  __syncthreads();

  // ---- GEMM4 (16x16x32): wave wid owns rows 16*wid..+16 (one (q,c) group)
  bf16x8s B4[2];
  const bf16x8s* fb4v = (const bf16x8s*)fb4;
  B4[0] = fb4v[l];
  B4[1] = fb4v[64 + l];
  f32x4 acc4;
#pragma unroll
  for (int i = 0; i < 4; ++i) acc4[i] = 0.f;
  {
    const unsigned char* abase = h3s + (16 * wid + l15) * 128;
#pragma unroll
    for (int ks = 0; ks < 2; ++ks) {
      const bf16x8s a =
          *(const bf16x8s*)(abase + ((((l >> 4) * 16) + ks * 64) ^ sw));
      acc4 = __builtin_amdgcn_mfma_f32_16x16x32_bf16(a, B4[ks], acc4, 0, 0, 0);
    }
  }

  // ---- epilogue: tanh, sum 10 cols, mean, sum 16 rows -> score
  {
    const int col = l15;
    const float b4v = (col < H4N) ? b4[col] : 0.f;
    float part = 0.f;
#pragma unroll
    for (int r = 0; r < 4; ++r) {
      const float v = tanhf(acc4[r] + b4v);
      part += (col < H4N) ? v : 0.f;
    }
    part += __shfl_xor(part, 1);
    part += __shfl_xor(part, 2);
    part += __shfl_xor(part, 4);
    part += __shfl_xor(part, 8);
    part += __shfl_xor(part, 16);
    part += __shfl_xor(part, 32);
    if (l == 0) out[(size_t)blockIdx.x * 4 + wid] = part * 0.1f;
  }
}

// ---------------------------------------------------------------------------
extern "C" void kernel_launch(void* const* d_in, const int* in_sizes, int n_in,
                              void* d_out, int out_size, void* d_ws, size_t ws_size,
                              hipStream_t stream) {
  const float* queries  = (const float*)d_in[0];
  const float* supports = (const float*)d_in[1];
  const float* W1 = (const float*)d_in[2];
  const float* b1 = (const float*)d_in[3];
  const float* W2 = (const float*)d_in[4];
  const float* b2 = (const float*)d_in[5];
  const float* W3 = (const float*)d_in[6];
  const float* b3 = (const float*)d_in[7];
  const float* W4 = (const float*)d_in[8];
  const float* b4 = (const float*)d_in[9];
  float* out = (float*)d_out;

  // workspace layout (fp32 A/Bm, then bf16 fragment buffers) ~2.35 MB
  float* A  = (float*)d_ws;                       // [2048][256]
  float* Bm = A + (size_t)QN * H1N;               // [160][256]
  ushort* fb2 = (ushort*)(Bm + (size_t)NROW * H1N);  // 64*512
  ushort* fb3 = fb2 + 64 * 512;                      // 16*512
  ushort* fb4 = fb3 + 16 * 512;                      // 2*512

  hipLaunchKernelGGL(k_pre, dim3(QN / 4 + NROW / 4), dim3(256), 0, stream,
                     queries, supports, W1, b1, A, Bm);
  hipLaunchKernelGGL(k_wpack, dim3(82), dim3(64), 0, stream,
                     W2, W3, W4, fb2, fb3, fb4);
  hipLaunchKernelGGL(k_main, dim3((QN * CN * SN) / 64), dim3(256), 0, stream,
                     A, Bm, fb2, fb3, fb4, b2, b3, b4, out);
}